// Round 1
// baseline (2396.789 us; speedup 1.0000x reference)
//
#include <hip/hip_runtime.h>
#include <math.h>

#define B_ 4
#define L_ 1024
#define DMODEL 512
#define NH 8
#define HD 64
#define DFF 2048
#define KSAMP 35

// ---------------- embed + positional encoding ----------------
__global__ __launch_bounds__(512) void embed_kernel(const float* __restrict__ src,
    const float* __restrict__ Wemb, const float* __restrict__ bemb, float* __restrict__ X)
{
  int row = blockIdx.x;          // b*L + l
  int l = row & (L_ - 1);
  int t = threadIdx.x;           // d in [0,512)
  __shared__ float s_src[32];
  if (t < 32) s_src[t] = src[row * 32 + t];
  __syncthreads();
  float acc = bemb[t];
  #pragma unroll
  for (int k = 0; k < 32; k++) acc += s_src[k] * Wemb[k * DMODEL + t];
  int i2 = t & ~1;
  float freq = expf((float)i2 * (-9.210340371976184f / 512.0f)); // -ln(10000)/512 * 2i
  float ang = (float)l * freq;
  acc += (t & 1) ? cosf(ang) : sinf(ang);
  X[(size_t)row * DMODEL + t] = acc;
}

// ---------------- generic tiled SGEMM: C = A@W + bias (epilogues) ----------------
__device__ inline float gelu_exact(float x) {
  return 0.5f * x * (1.0f + erff(x * 0.7071067811865476f));
}

__global__ __launch_bounds__(256) void gemm_kernel(
    const float* __restrict__ A, const float* __restrict__ W,
    const float* __restrict__ bias, const float* __restrict__ R,
    float* __restrict__ C, int M, int N, int K, int mode)
{
  __shared__ float As[16][65];
  __shared__ float Ws[16][65];
  int t = threadIdx.x;
  int tx = t & 15, ty = t >> 4;
  int row0 = blockIdx.y * 64, col0 = blockIdx.x * 64;
  float acc[4][4] = {};
  for (int kt = 0; kt < K; kt += 16) {
    #pragma unroll
    for (int i = 0; i < 4; i++) {
      int idx = t + i * 256;
      int r = idx >> 4, kk = idx & 15;
      As[kk][r] = A[(size_t)(row0 + r) * K + kt + kk];
      int kw = idx >> 6, c = idx & 63;
      Ws[kw][c] = W[(size_t)(kt + kw) * N + col0 + c];
    }
    __syncthreads();
    #pragma unroll
    for (int kk = 0; kk < 16; kk++) {
      float a[4], w[4];
      #pragma unroll
      for (int i = 0; i < 4; i++) a[i] = As[kk][ty * 4 + i];
      #pragma unroll
      for (int j = 0; j < 4; j++) w[j] = Ws[kk][tx * 4 + j];
      #pragma unroll
      for (int i = 0; i < 4; i++)
        #pragma unroll
        for (int j = 0; j < 4; j++)
          acc[i][j] += a[i] * w[j];
    }
    __syncthreads();
  }
  #pragma unroll
  for (int i = 0; i < 4; i++) {
    int r = row0 + ty * 4 + i;
    #pragma unroll
    for (int j = 0; j < 4; j++) {
      int c = col0 + tx * 4 + j;
      float v = acc[i][j] + bias[c];
      if (mode == 1) v = gelu_exact(v);
      else if (mode == 2) v += R[(size_t)r * N + c];
      C[(size_t)r * N + c] = v;
    }
  }
}

// ---------------- QK_sample -> M score ----------------
__global__ __launch_bounds__(64) void qksample_kernel(
    const float* __restrict__ Qf, const float* __restrict__ Kf,
    const int* __restrict__ idx_s, float* __restrict__ Msc)
{
  int gid = blockIdx.x;          // (b*8+h)*1024 + i
  int i = gid & (L_ - 1);
  int h = (gid >> 10) & 7;
  int b = gid >> 13;
  int e = threadIdx.x;
  float q = Qf[((size_t)(b * L_ + i)) * DMODEL + h * HD + e];
  float mx = -3.4e38f, sm = 0.f;
  for (int j = 0; j < KSAMP; j++) {
    int s = idx_s[i * KSAMP + j];
    float p = q * Kf[((size_t)(b * L_ + s)) * DMODEL + h * HD + e];
    #pragma unroll
    for (int off = 32; off > 0; off >>= 1) p += __shfl_xor(p, off);
    mx = fmaxf(mx, p);
    sm += p;
  }
  if (e == 0) Msc[gid] = mx - sm * (1.0f / KSAMP);
}

// ---------------- top-35 per (b,h), tie-break lower index ----------------
__global__ __launch_bounds__(256) void topk_kernel(const float* __restrict__ Msc, int* __restrict__ idx_top)
{
  int bh = blockIdx.x;
  int t = threadIdx.x;
  __shared__ float vals[L_];
  __shared__ float rv[256];
  __shared__ int ri[256];
  for (int i = t; i < L_; i += 256) vals[i] = Msc[(size_t)bh * L_ + i];
  __syncthreads();
  for (int sel = 0; sel < KSAMP; sel++) {
    float bv = -3.4e38f; int bi = 0x7fffffff;
    for (int i = t; i < L_; i += 256) {
      float v = vals[i];
      if (v > bv || (v == bv && i < bi)) { bv = v; bi = i; }
    }
    rv[t] = bv; ri[t] = bi;
    __syncthreads();
    for (int s = 128; s > 0; s >>= 1) {
      if (t < s) {
        if (rv[t + s] > rv[t] || (rv[t + s] == rv[t] && ri[t + s] < ri[t])) {
          rv[t] = rv[t + s]; ri[t] = ri[t + s];
        }
      }
      __syncthreads();
    }
    if (t == 0) { idx_top[bh * KSAMP + sel] = ri[0]; vals[ri[0]] = -3.4e38f; }
    __syncthreads();
  }
}

// ---------------- dense attention for the 35 selected queries ----------------
__global__ __launch_bounds__(64) void attn_kernel(
    const float* __restrict__ Qf, const float* __restrict__ Kf, const float* __restrict__ Vf,
    const int* __restrict__ idx_top, float* __restrict__ ctx_top)
{
  int gid = blockIdx.x;   // (b*8+h)*35 + u
  int bh = gid / KSAMP;
  int h = bh & 7, b = bh >> 3;
  int e = threadIdx.x;
  int qi = idx_top[gid];
  float q = Qf[((size_t)(b * L_ + qi)) * DMODEL + h * HD + e] * 0.125f; // 1/sqrt(64)
  float m = -3.4e38f, l = 0.f, acc = 0.f;
  for (int s = 0; s < L_; s++) {
    size_t base = ((size_t)(b * L_ + s)) * DMODEL + h * HD + e;
    float p = q * Kf[base];
    #pragma unroll
    for (int off = 32; off > 0; off >>= 1) p += __shfl_xor(p, off);
    float nm = fmaxf(m, p);
    float corr = expf(m - nm);
    float w = expf(p - nm);
    l = l * corr + w;
    acc = acc * corr + w * Vf[base];
    m = nm;
  }
  ctx_top[(size_t)gid * HD + e] = acc / l;
}

// ---------------- V mean over L ----------------
__global__ __launch_bounds__(64) void vmean_kernel(const float* __restrict__ Vf, float* __restrict__ Vmean)
{
  int bh = blockIdx.x;
  int h = bh & 7, b = bh >> 3;
  int e = threadIdx.x;
  float s = 0.f;
  for (int l = 0; l < L_; l++) s += Vf[((size_t)(b * L_ + l)) * DMODEL + h * HD + e];
  Vmean[bh * HD + e] = s * (1.0f / L_);
}

// ---------------- context: broadcast V-mean then scatter top rows ----------------
__global__ __launch_bounds__(512) void ctxfill_kernel(const float* __restrict__ Vmean, float* __restrict__ CTX)
{
  int row = blockIdx.x; // b*L + l
  int b = row >> 10;
  int t = threadIdx.x;  // d = h*64+e  -> Vmean[b*512 + d]
  CTX[(size_t)row * DMODEL + t] = Vmean[b * DMODEL + t];
}

__global__ __launch_bounds__(64) void ctxscatter_kernel(const int* __restrict__ idx_top,
    const float* __restrict__ ctx_top, float* __restrict__ CTX)
{
  int gid = blockIdx.x; // (b*8+h)*35+u
  int bh = gid / KSAMP;
  int h = bh & 7, b = bh >> 3;
  int e = threadIdx.x;
  int qi = idx_top[gid];
  CTX[((size_t)(b * L_ + qi)) * DMODEL + h * HD + e] = ctx_top[(size_t)gid * HD + e];
}

// ---------------- LayerNorm (optionally sum of two inputs) ----------------
__global__ __launch_bounds__(512) void ln_kernel(const float* __restrict__ Xa, const float* __restrict__ Xb,
    const float* __restrict__ g, const float* __restrict__ beta, float* __restrict__ out)
{
  int row = blockIdx.x;
  int t = threadIdx.x;
  __shared__ float red[512];
  float v = Xa[(size_t)row * DMODEL + t];
  if (Xb) v += Xb[(size_t)row * DMODEL + t];
  red[t] = v; __syncthreads();
  for (int s = 256; s > 0; s >>= 1) { if (t < s) red[t] += red[t + s]; __syncthreads(); }
  float mean = red[0] * (1.0f / DMODEL);
  __syncthreads();
  float d = v - mean;
  red[t] = d * d; __syncthreads();
  for (int s = 256; s > 0; s >>= 1) { if (t < s) red[t] += red[t + s]; __syncthreads(); }
  float var = red[0] * (1.0f / DMODEL);
  out[(size_t)row * DMODEL + t] = d / sqrtf(var + 1e-5f) * g[t] + beta[t];
}

// ---------------- mean pool over L ----------------
__global__ __launch_bounds__(512) void pool_kernel(const float* __restrict__ X, float* __restrict__ pooled)
{
  int b = blockIdx.x;
  int t = threadIdx.x;
  float s = 0.f;
  for (int l = 0; l < L_; l++) s += X[((size_t)(b * L_ + l)) * DMODEL + t];
  pooled[b * DMODEL + t] = s * (1.0f / L_);
}

// ---------------- classifier head ----------------
__global__ __launch_bounds__(64) void cls_kernel(const float* __restrict__ pooled,
    const float* __restrict__ Wc, const float* __restrict__ bc, float* __restrict__ out)
{
  int t = threadIdx.x;
  if (t < 40) {
    int b = t / 10, c = t % 10;
    float s = bc[c];
    for (int d = 0; d < DMODEL; d++) s += pooled[b * DMODEL + d] * Wc[d * 10 + c];
    out[t] = s;
  }
}

extern "C" void kernel_launch(void* const* d_in, const int* in_sizes, int n_in,
                              void* d_out, int out_size, void* d_ws, size_t ws_size,
                              hipStream_t stream)
{
  const float* src   = (const float*)d_in[0];
  const int*   idxs  = (const int*)d_in[1];
  const float* Wemb  = (const float*)d_in[2];
  const float* bemb  = (const float*)d_in[3];
  const float* Wq    = (const float*)d_in[4];
  const float* bq    = (const float*)d_in[5];
  const float* Wk    = (const float*)d_in[6];
  const float* bk    = (const float*)d_in[7];
  const float* Wv    = (const float*)d_in[8];
  const float* bv    = (const float*)d_in[9];
  const float* Wo    = (const float*)d_in[10];
  const float* bo    = (const float*)d_in[11];
  const float* g1    = (const float*)d_in[12];
  const float* beta1 = (const float*)d_in[13];
  const float* W1    = (const float*)d_in[14];
  const float* bf1   = (const float*)d_in[15];
  const float* W2    = (const float*)d_in[16];
  const float* bf2   = (const float*)d_in[17];
  const float* g2    = (const float*)d_in[18];
  const float* beta2 = (const float*)d_in[19];
  const float* gf    = (const float*)d_in[20];
  const float* betaf = (const float*)d_in[21];
  const float* Wc    = (const float*)d_in[22];
  const float* bc    = (const float*)d_in[23];
  float* out = (float*)d_out;

  const size_t EL = (size_t)B_ * L_ * DMODEL; // 2,097,152 elements
  float* X    = (float*)d_ws;
  float* Qf   = X + EL;
  float* Kf   = X + 2 * EL;
  float* Vf   = X + 3 * EL;
  float* CTX  = X + 4 * EL;
  float* Hff  = Qf;            // alias: spans Qf..CTX end == 4*EL == B*L*DFF, QKV dead by then
  float* Yff  = X + 5 * EL;
  float* Msc  = X + 6 * EL;                              // B*H*L = 32768
  float* ctxt = Msc + (size_t)B_ * NH * L_;              // B*H*35*64 = 71680
  float* Vmean = ctxt + (size_t)B_ * NH * KSAMP * HD;    // 2048
  float* pooled = Vmean + B_ * NH * HD;                  // 2048
  int* idx_top = (int*)(pooled + B_ * DMODEL);           // 1120 ints

  const int M = B_ * L_; // 4096
  embed_kernel<<<M, 512, 0, stream>>>(src, Wemb, bemb, X);

  for (int layer = 0; layer < 2; layer++) {
    const size_t wo  = (size_t)layer * DMODEL * DMODEL;
    const size_t vo  = (size_t)layer * DMODEL;
    dim3 g512(DMODEL / 64, M / 64), g2048(DFF / 64, M / 64);
    gemm_kernel<<<g512, 256, 0, stream>>>(X, Wq + wo, bq + vo, nullptr, Qf, M, DMODEL, DMODEL, 0);
    gemm_kernel<<<g512, 256, 0, stream>>>(X, Wk + wo, bk + vo, nullptr, Kf, M, DMODEL, DMODEL, 0);
    gemm_kernel<<<g512, 256, 0, stream>>>(X, Wv + wo, bv + vo, nullptr, Vf, M, DMODEL, DMODEL, 0);
    qksample_kernel<<<B_ * NH * L_, 64, 0, stream>>>(Qf, Kf, idxs + (size_t)layer * L_ * KSAMP, Msc);
    topk_kernel<<<B_ * NH, 256, 0, stream>>>(Msc, idx_top);
    attn_kernel<<<B_ * NH * KSAMP, 64, 0, stream>>>(Qf, Kf, Vf, idx_top, ctxt);
    vmean_kernel<<<B_ * NH, 64, 0, stream>>>(Vf, Vmean);
    ctxfill_kernel<<<M, 512, 0, stream>>>(Vmean, CTX);
    ctxscatter_kernel<<<B_ * NH * KSAMP, 64, 0, stream>>>(idx_top, ctxt, CTX);
    gemm_kernel<<<g512, 256, 0, stream>>>(CTX, Wo + wo, bo + vo, X, X, M, DMODEL, DMODEL, 2);
    ln_kernel<<<M, 512, 0, stream>>>(X, nullptr, g1 + vo, beta1 + vo, X);
    gemm_kernel<<<g2048, 256, 0, stream>>>(X, W1 + (size_t)layer * DMODEL * DFF, bf1 + (size_t)layer * DFF,
                                           nullptr, Hff, M, DFF, DMODEL, 1);
    gemm_kernel<<<g512, 256, 0, stream>>>(Hff, W2 + (size_t)layer * DFF * DMODEL, bf2 + vo, nullptr, Yff, M, DMODEL, DFF, 0);
    ln_kernel<<<M, 512, 0, stream>>>(X, Yff, g2 + vo, beta2 + vo, X);
  }
  ln_kernel<<<M, 512, 0, stream>>>(X, nullptr, gf, betaf, X);
  pool_kernel<<<B_, 512, 0, stream>>>(X, pooled);
  cls_kernel<<<1, 64, 0, stream>>>(pooled, Wc, bc, out);
}

// Round 2
// 943.900 us; speedup vs baseline: 2.5392x; 2.5392x over previous
//
#include <hip/hip_runtime.h>
#include <hip/hip_bf16.h>
#include <math.h>

#define B_ 4
#define L_ 1024
#define DM 512
#define NH 8
#define HD 64
#define DFF 2048
#define KS 35
#define QS 1536   // packed QKV row stride

typedef __attribute__((ext_vector_type(8))) short bf16x8;
typedef __attribute__((ext_vector_type(4))) float f32x4;

__device__ inline ushort f2b(float f){
  __hip_bfloat16 h = __float2bfloat16(f);
  return *reinterpret_cast<ushort*>(&h);
}
__device__ inline float gelu_exact(float x){
  return 0.5f*x*(1.0f+erff(x*0.7071067811865476f));
}

#define GLOAD16(g, l) __builtin_amdgcn_global_load_lds( \
    (const __attribute__((address_space(1))) void*)(g), \
    (__attribute__((address_space(3))) void*)(l), 16, 0, 0)

// ---------------- weight convert + transpose to bf16 [N][K] ----------------
__global__ __launch_bounds__(256) void wconv_kernel(const float* __restrict__ W,
    ushort* __restrict__ Wt, int K, int N)
{
  __shared__ float tile[32][33];
  int n0 = blockIdx.x*32, k0 = blockIdx.y*32;
  int tx = threadIdx.x & 31, ty = threadIdx.x >> 5;
  #pragma unroll
  for (int i = ty; i < 32; i += 8) tile[i][tx] = W[(size_t)(k0+i)*N + n0+tx];
  __syncthreads();
  #pragma unroll
  for (int i = ty; i < 32; i += 8) Wt[(size_t)(n0+i)*K + k0+tx] = f2b(tile[tx][i]);
}

__global__ __launch_bounds__(256) void bcat_kernel(const float* __restrict__ bq,
    const float* __restrict__ bk, const float* __restrict__ bv, float* __restrict__ bqkv)
{
  int i = blockIdx.x*256 + threadIdx.x;   // 0..3071
  if (i >= 2*QS) return;
  int l = i / QS, j = i - l*QS;
  const float* src = (j < 512) ? bq : (j < 1024 ? bk : bv);
  bqkv[i] = src[l*DM + (j & 511)];
}

// ---------------- bf16 MFMA GEMM: C = A @ Bt^T + bias (epilogues) ----------------
// A: [M][K] bf16 row-major; Bt: [N][K] bf16; MODE 0: f32 out, 1: gelu->bf16 out, 2: +R f32 out
template<int BN, int MODE>
__global__ __launch_bounds__(256) void mfma_gemm(
    const ushort* __restrict__ A, const ushort* __restrict__ Bt,
    const float* __restrict__ bias, const float* __restrict__ R,
    float* __restrict__ Cf, ushort* __restrict__ Cb,
    int M, int N, int K)
{
  constexpr int BM = 128, BK = 32;
  constexpr int NF = BN/32;          // B fragments per wave
  constexpr int ACH = BM*4;          // 16B chunks in A tile
  constexpr int BCH = BN*4;
  __shared__ __align__(16) ushort As[BM*BK];
  __shared__ __align__(16) ushort Bs[BN*BK];
  const int t = threadIdx.x, lane = t & 63, w = t >> 6, wr = w >> 1, wc = w & 1;
  const int row0 = blockIdx.y*BM, col0 = blockIdx.x*BN;

  // staging addresses: linear LDS dest, inverse-swizzled global source
  const ushort* aSrc[ACH/256]; int aDst[ACH/256];
  #pragma unroll
  for (int j = 0; j < ACH/256; j++) {
    int ch = j*256 + t, r = ch >> 2, c = ch & 3, cs = c ^ ((r >> 1) & 3);
    aSrc[j] = A + (size_t)(row0 + r)*K + cs*8;
    aDst[j] = ch*16;
  }
  const ushort* bSrc[BCH/256]; int bDst[BCH/256];
  #pragma unroll
  for (int j = 0; j < BCH/256; j++) {
    int ch = j*256 + t, r = ch >> 2, c = ch & 3, cs = c ^ ((r >> 1) & 3);
    bSrc[j] = Bt + (size_t)(col0 + r)*K + cs*8;
    bDst[j] = ch*16;
  }
  // fragment read offsets (swizzled)
  int aOff[4], bOff[NF];
  #pragma unroll
  for (int m = 0; m < 4; m++) {
    int r = wr*64 + m*16 + (lane & 15);
    aOff[m] = r*64 + (((lane >> 4)*16) ^ (((r >> 1) & 3) << 4));
  }
  #pragma unroll
  for (int n = 0; n < NF; n++) {
    int r = wc*(BN/2) + n*16 + (lane & 15);
    bOff[n] = r*64 + (((lane >> 4)*16) ^ (((r >> 1) & 3) << 4));
  }
  f32x4 zero = {0.f, 0.f, 0.f, 0.f};
  f32x4 acc[4][NF];
  #pragma unroll
  for (int m = 0; m < 4; m++)
    #pragma unroll
    for (int n = 0; n < NF; n++) acc[m][n] = zero;

  for (int kt = 0; kt < K; kt += BK) {
    __syncthreads();
    #pragma unroll
    for (int j = 0; j < ACH/256; j++) GLOAD16(aSrc[j] + kt, (char*)As + aDst[j]);
    #pragma unroll
    for (int j = 0; j < BCH/256; j++) GLOAD16(bSrc[j] + kt, (char*)Bs + bDst[j]);
    __syncthreads();
    bf16x8 af[4], bfr[NF];
    #pragma unroll
    for (int m = 0; m < 4; m++) af[m] = *(const bf16x8*)((const char*)As + aOff[m]);
    #pragma unroll
    for (int n = 0; n < NF; n++) bfr[n] = *(const bf16x8*)((const char*)Bs + bOff[n]);
    #pragma unroll
    for (int m = 0; m < 4; m++)
      #pragma unroll
      for (int n = 0; n < NF; n++)
        acc[m][n] = __builtin_amdgcn_mfma_f32_16x16x32_bf16(af[m], bfr[n], acc[m][n], 0, 0, 0);
  }
  #pragma unroll
  for (int m = 0; m < 4; m++) {
    int rb = row0 + wr*64 + m*16 + ((lane >> 4) << 2);
    #pragma unroll
    for (int n = 0; n < NF; n++) {
      int c = col0 + wc*(BN/2) + n*16 + (lane & 15);
      float bv = bias[c];
      #pragma unroll
      for (int j = 0; j < 4; j++) {
        size_t idx = (size_t)(rb + j)*N + c;
        float v = acc[m][n][j] + bv;
        if (MODE == 1)      Cb[idx] = f2b(gelu_exact(v));
        else if (MODE == 2) Cf[idx] = v + R[idx];
        else                Cf[idx] = v;
      }
    }
  }
}

// ---------------- embed + positional encoding ----------------
__global__ __launch_bounds__(512) void embed_kernel(const float* __restrict__ src,
    const float* __restrict__ Wemb, const float* __restrict__ bemb,
    float* __restrict__ X, ushort* __restrict__ Xb)
{
  int row = blockIdx.x, l = row & (L_-1), t = threadIdx.x;
  __shared__ float s_src[32];
  if (t < 32) s_src[t] = src[row*32 + t];
  __syncthreads();
  float acc = bemb[t];
  #pragma unroll
  for (int k = 0; k < 32; k++) acc += s_src[k]*Wemb[k*DM + t];
  int i2 = t & ~1;
  float freq = expf((float)i2 * (-9.210340371976184f/512.0f));
  float ang = (float)l * freq;
  acc += (t & 1) ? cosf(ang) : sinf(ang);
  size_t idx = (size_t)row*DM + t;
  X[idx] = acc;
  Xb[idx] = f2b(acc);
}

// ---------------- QK_sample -> M score ----------------
__global__ __launch_bounds__(64) void qksample_kernel(const float* __restrict__ QKV,
    const int* __restrict__ idx_s, float* __restrict__ Msc)
{
  int gid = blockIdx.x;
  int i = gid & (L_-1), h = (gid >> 10) & 7, b = gid >> 13;
  int e = threadIdx.x;
  float q = QKV[((size_t)(b*L_ + i))*QS + h*HD + e];
  float mx = -3.4e38f, sm = 0.f;
  for (int j = 0; j < KS; j++) {
    int s = idx_s[i*KS + j];
    float p = q * QKV[((size_t)(b*L_ + s))*QS + 512 + h*HD + e];
    #pragma unroll
    for (int off = 32; off; off >>= 1) p += __shfl_xor(p, off);
    mx = fmaxf(mx, p); sm += p;
  }
  if (e == 0) Msc[gid] = mx - sm*(1.0f/KS);
}

// ---------------- single-wave top-35 (tie-break lower index) ----------------
__global__ __launch_bounds__(64) void topk_kernel(const float* __restrict__ Msc, int* __restrict__ idx_top)
{
  int bh = blockIdx.x, t = threadIdx.x;
  __shared__ float vals[L_];
  for (int i = t; i < L_; i += 64) vals[i] = Msc[(size_t)bh*L_ + i];
  __syncthreads();
  for (int sel = 0; sel < KS; sel++) {
    float bv = -3.4e38f; int bi = 0x7fffffff;
    for (int i = t; i < L_; i += 64) {
      float v = vals[i];
      if (v > bv || (v == bv && i < bi)) { bv = v; bi = i; }
    }
    #pragma unroll
    for (int off = 32; off; off >>= 1) {
      float ov = __shfl_xor(bv, off); int oi = __shfl_xor(bi, off);
      if (ov > bv || (ov == bv && oi < bi)) { bv = ov; bi = oi; }
    }
    if (t == 0) idx_top[bh*KS + sel] = bi;
    if (t == (bi & 63)) vals[bi] = -3.4e38f;
    __syncthreads();
  }
}

// ---------------- V mean over L ----------------
__global__ __launch_bounds__(256) void vmean_kernel(const float* __restrict__ QKV, float* __restrict__ Vmean)
{
  int bh = blockIdx.x, h = bh & 7, b = bh >> 3;
  int g = threadIdx.x >> 6, e = threadIdx.x & 63;
  __shared__ float p[4][64];
  const float* Vb = QKV + 1024 + h*HD + (size_t)b*L_*QS;
  float s = 0.f;
  for (int l = g; l < L_; l += 4) s += Vb[(size_t)l*QS + e];
  p[g][e] = s;
  __syncthreads();
  if (threadIdx.x < 64)
    Vmean[bh*HD + threadIdx.x] =
      (p[0][threadIdx.x]+p[1][threadIdx.x]+p[2][threadIdx.x]+p[3][threadIdx.x]) * (1.f/L_);
}

// ---------------- fill context with broadcast V-mean (bf16) ----------------
__global__ __launch_bounds__(512) void ctxfill_kernel(const float* __restrict__ Vmean, ushort* __restrict__ CTXb)
{
  int row = blockIdx.x, b = row >> 10, t = threadIdx.x;
  CTXb[(size_t)row*DM + t] = f2b(Vmean[b*DM + t]);
}

// ---------------- key-parallel attention for the 35 selected queries ----------------
__global__ __launch_bounds__(256) void attn_kernel(const float* __restrict__ QKV,
    const int* __restrict__ idx_top, ushort* __restrict__ CTXb)
{
  int gid = blockIdx.x;          // (b*8+h)*35+u
  int bh = gid / KS, h = bh & 7, b = bh >> 3;
  int qi = idx_top[gid];
  int t = threadIdx.x;
  __shared__ float sc[L_];
  __shared__ float4 qv[16];
  __shared__ float red[8];
  __shared__ float pacc[4][64];
  const float* Qrow = QKV + ((size_t)(b*L_ + qi))*QS + h*HD;
  if (t < 16) {
    float4 q4 = *(const float4*)(Qrow + t*4);
    q4.x *= 0.125f; q4.y *= 0.125f; q4.z *= 0.125f; q4.w *= 0.125f;
    qv[t] = q4;
  }
  __syncthreads();
  const float* Kb = QKV + 512 + h*HD + (size_t)b*L_*QS;
  for (int s = t; s < L_; s += 256) {
    const float4* Kr = (const float4*)(Kb + (size_t)s*QS);
    float d = 0.f;
    #pragma unroll
    for (int e = 0; e < 16; e++) {
      float4 k4 = Kr[e], q4 = qv[e];
      d += q4.x*k4.x + q4.y*k4.y + q4.z*k4.z + q4.w*k4.w;
    }
    sc[s] = d;
  }
  __syncthreads();
  float m = -3.4e38f;
  for (int s = t; s < L_; s += 256) m = fmaxf(m, sc[s]);
  #pragma unroll
  for (int off = 32; off; off >>= 1) m = fmaxf(m, __shfl_xor(m, off));
  if ((t & 63) == 0) red[t >> 6] = m;
  __syncthreads();
  m = fmaxf(fmaxf(red[0], red[1]), fmaxf(red[2], red[3]));
  float lsum = 0.f;
  for (int s = t; s < L_; s += 256) { float wv = expf(sc[s] - m); sc[s] = wv; lsum += wv; }
  #pragma unroll
  for (int off = 32; off; off >>= 1) lsum += __shfl_xor(lsum, off);
  if ((t & 63) == 0) red[4 + (t >> 6)] = lsum;
  __syncthreads();
  lsum = red[4] + red[5] + red[6] + red[7];
  int g = t >> 6, e = t & 63;
  const float* Vb = QKV + 1024 + h*HD + (size_t)b*L_*QS;
  float a = 0.f;
  for (int s = g*256; s < g*256 + 256; s++) a += sc[s] * Vb[(size_t)s*QS + e];
  pacc[g][e] = a;
  __syncthreads();
  if (t < 64) {
    float r = (pacc[0][t] + pacc[1][t] + pacc[2][t] + pacc[3][t]) / lsum;
    CTXb[((size_t)(b*L_ + qi))*DM + h*HD + t] = f2b(r);
  }
}

// ---------------- LayerNorm (optional add), f32 + bf16 out ----------------
__global__ __launch_bounds__(512) void ln_kernel(const float* __restrict__ Xa,
    const float* __restrict__ Xadd, const float* __restrict__ g, const float* __restrict__ beta,
    float* __restrict__ outf, ushort* __restrict__ outb)
{
  int row = blockIdx.x, t = threadIdx.x;
  __shared__ float red[16];
  size_t idx = (size_t)row*DM + t;
  float v = Xa[idx];
  if (Xadd) v += Xadd[idx];
  float s = v;
  #pragma unroll
  for (int off = 32; off; off >>= 1) s += __shfl_xor(s, off);
  if ((t & 63) == 0) red[t >> 6] = s;
  __syncthreads();
  float mean = 0.f;
  #pragma unroll
  for (int k = 0; k < 8; k++) mean += red[k];
  mean *= (1.f/DM);
  float d = v - mean, q = d*d;
  #pragma unroll
  for (int off = 32; off; off >>= 1) q += __shfl_xor(q, off);
  if ((t & 63) == 0) red[8 + (t >> 6)] = q;
  __syncthreads();
  float var = 0.f;
  #pragma unroll
  for (int k = 0; k < 8; k++) var += red[8 + k];
  var *= (1.f/DM);
  float r = d / sqrtf(var + 1e-5f) * g[t] + beta[t];
  outf[idx] = r;
  if (outb) outb[idx] = f2b(r);
}

// ---------------- partial mean pool + classifier ----------------
__global__ __launch_bounds__(512) void poolp_kernel(const float* __restrict__ X, float* __restrict__ pooledP)
{
  int p = blockIdx.x;            // b*8+seg
  int t = threadIdx.x;
  int b = p >> 3, seg = p & 7;
  float s = 0.f;
  const float* base = X + ((size_t)b*L_ + seg*128)*DM + t;
  for (int l = 0; l < 128; l++) s += base[(size_t)l*DM];
  pooledP[p*DM + t] = s;
}

__global__ __launch_bounds__(64) void cls_kernel(const float* __restrict__ pooledP,
    const float* __restrict__ Wc, const float* __restrict__ bc, float* __restrict__ out)
{
  int o = blockIdx.x;            // 0..39
  int b = o/10, c = o%10, t = threadIdx.x;
  float s = 0.f;
  for (int d = t; d < DM; d += 64) {
    float p = 0.f;
    #pragma unroll
    for (int seg = 0; seg < 8; seg++) p += pooledP[(b*8 + seg)*DM + d];
    s += p * (1.f/L_) * Wc[d*10 + c];
  }
  #pragma unroll
  for (int off = 32; off; off >>= 1) s += __shfl_xor(s, off);
  if (t == 0) out[o] = bc[c] + s;
}

extern "C" void kernel_launch(void* const* d_in, const int* in_sizes, int n_in,
                              void* d_out, int out_size, void* d_ws, size_t ws_size,
                              hipStream_t stream)
{
  const float* src   = (const float*)d_in[0];
  const int*   idxs  = (const int*)d_in[1];
  const float* Wemb  = (const float*)d_in[2];
  const float* bemb  = (const float*)d_in[3];
  const float* Wq    = (const float*)d_in[4];
  const float* bq    = (const float*)d_in[5];
  const float* Wk    = (const float*)d_in[6];
  const float* bk    = (const float*)d_in[7];
  const float* Wv    = (const float*)d_in[8];
  const float* bv    = (const float*)d_in[9];
  const float* Wo    = (const float*)d_in[10];
  const float* bo    = (const float*)d_in[11];
  const float* g1    = (const float*)d_in[12];
  const float* beta1 = (const float*)d_in[13];
  const float* W1    = (const float*)d_in[14];
  const float* bf1   = (const float*)d_in[15];
  const float* W2    = (const float*)d_in[16];
  const float* bf2   = (const float*)d_in[17];
  const float* g2    = (const float*)d_in[18];
  const float* beta2 = (const float*)d_in[19];
  const float* gf    = (const float*)d_in[20];
  const float* betaf = (const float*)d_in[21];
  const float* Wc    = (const float*)d_in[22];
  const float* bc    = (const float*)d_in[23];
  float* out = (float*)d_out;

  float* wsf = (float*)d_ws;
  // float-unit offsets
  float*  X     = wsf;                              // 2,097,152
  ushort* Xb    = (ushort*)(wsf + 2097152);         // 1,048,576 fl
  ushort* CTXb  = (ushort*)(wsf + 3145728);         // 1,048,576 fl
  float*  QKV   = wsf + 4194304;                    // 6,291,456 fl (aliased by H+Y later)
  ushort* H     = (ushort*)(wsf + 4194304);         // 4,194,304 fl
  float*  Y     = wsf + 8388608;                    // 2,097,152 fl
  ushort* Wqkvt = (ushort*)(wsf + 10485760);        // 786,432 fl
  ushort* Wot   = (ushort*)(wsf + 11272192);        // 262,144 fl
  ushort* W1t   = (ushort*)(wsf + 11534336);        // 1,048,576 fl
  ushort* W2t   = (ushort*)(wsf + 12582912);        // 1,048,576 fl
  float*  bqkv  = wsf + 13631488;                   // 3,072
  float*  Msc   = wsf + 13634560;                   // 32,768
  float*  Vmean = wsf + 13667328;                   // 2,048
  float*  pooledP = wsf + 13669376;                 // 16,384
  int*    idx_top = (int*)(wsf + 13685760);         // 1,120

  // --- weight conversion (bf16, transposed [N][K]) ---
  for (int l = 0; l < 2; l++) {
    wconv_kernel<<<dim3(DM/32, DM/32), 256, 0, stream>>>(Wq + (size_t)l*DM*DM, Wqkvt + ((size_t)l*QS +    0)*DM, DM, DM);
    wconv_kernel<<<dim3(DM/32, DM/32), 256, 0, stream>>>(Wk + (size_t)l*DM*DM, Wqkvt + ((size_t)l*QS +  512)*DM, DM, DM);
    wconv_kernel<<<dim3(DM/32, DM/32), 256, 0, stream>>>(Wv + (size_t)l*DM*DM, Wqkvt + ((size_t)l*QS + 1024)*DM, DM, DM);
    wconv_kernel<<<dim3(DM/32, DM/32), 256, 0, stream>>>(Wo + (size_t)l*DM*DM, Wot + (size_t)l*DM*DM, DM, DM);
    wconv_kernel<<<dim3(DFF/32, DM/32), 256, 0, stream>>>(W1 + (size_t)l*DM*DFF, W1t + (size_t)l*DFF*DM, DM, DFF);
    wconv_kernel<<<dim3(DM/32, DFF/32), 256, 0, stream>>>(W2 + (size_t)l*DFF*DM, W2t + (size_t)l*DM*DFF, DFF, DM);
  }
  bcat_kernel<<<12, 256, 0, stream>>>(bq, bk, bv, bqkv);

  const int M = B_ * L_; // 4096
  embed_kernel<<<M, 512, 0, stream>>>(src, Wemb, bemb, X, Xb);

  for (int l = 0; l < 2; l++) {
    const size_t vo = (size_t)l*DM;
    // QKV fused GEMM: [4096,512] x [512,1536]
    mfma_gemm<128,0><<<dim3(QS/128, M/128), 256, 0, stream>>>(
        Xb, Wqkvt + (size_t)l*QS*DM, bqkv + (size_t)l*QS, nullptr, QKV, nullptr, M, QS, DM);
    qksample_kernel<<<B_*NH*L_, 64, 0, stream>>>(QKV, idxs + (size_t)l*L_*KS, Msc);
    topk_kernel<<<B_*NH, 64, 0, stream>>>(Msc, idx_top);
    vmean_kernel<<<B_*NH, 256, 0, stream>>>(QKV, Vmean);
    ctxfill_kernel<<<M, 512, 0, stream>>>(Vmean, CTXb);
    attn_kernel<<<B_*NH*KS, 256, 0, stream>>>(QKV, idx_top, CTXb);
    // Wo GEMM + residual -> X (f32)
    mfma_gemm<64,2><<<dim3(DM/64, M/128), 256, 0, stream>>>(
        CTXb, Wot + (size_t)l*DM*DM, bo + vo, X, X, nullptr, M, DM, DM);
    ln_kernel<<<M, 512, 0, stream>>>(X, nullptr, g1 + vo, beta1 + vo, X, Xb);
    // FFN
    mfma_gemm<128,1><<<dim3(DFF/128, M/128), 256, 0, stream>>>(
        Xb, W1t + (size_t)l*DFF*DM, bf1 + (size_t)l*DFF, nullptr, nullptr, H, M, DFF, DM);
    mfma_gemm<64,0><<<dim3(DM/64, M/128), 256, 0, stream>>>(
        H, W2t + (size_t)l*DM*DFF, bf2 + vo, nullptr, Y, nullptr, M, DM, DFF);
    ln_kernel<<<M, 512, 0, stream>>>(X, Y, g2 + vo, beta2 + vo, X, Xb);
  }
  ln_kernel<<<M, 512, 0, stream>>>(X, nullptr, gf, betaf, X, nullptr);
  poolp_kernel<<<B_*8, 512, 0, stream>>>(X, pooledP);
  cls_kernel<<<40, 64, 0, stream>>>(pooledP, Wc, bc, out);
}